// Round 2
// baseline (489.025 us; speedup 1.0000x reference)
//
#include <hip/hip_runtime.h>
#include <hip/hip_bf16.h>

typedef __attribute__((ext_vector_type(8))) short bf16x8;
typedef __attribute__((ext_vector_type(4))) float f32x4;

#define NT_TILES 6250   // 800000 / 128
#define NBLK     250    // 250 blocks x 25 tiles each, 1 block/CU
#define KPAD     232    // X row stride (224 + 8): b128 reads tile all 32 banks
#define NPAD     264    // H row stride (256 + 8)

__device__ __forceinline__ short f2bf(float x) {
  union { __hip_bfloat16 h; short s; } u; u.h = __float2bfloat16(x); return u.s;
}
__device__ __forceinline__ short4 pk4(float4 v) {
  short4 s; s.x = f2bf(v.x); s.y = f2bf(v.y); s.z = f2bf(v.z); s.w = f2bf(v.w);
  return s;
}

// Raw workgroup barrier: drains LDS ops (cross-wave visibility) but NOT vmcnt,
// so register-staged global prefetch loads stay in flight across it.
__device__ __forceinline__ void barrier_lds() {
  asm volatile("s_waitcnt lgkmcnt(0)" ::: "memory");
  __builtin_amdgcn_s_barrier();
}

// W1 [224][256] -> W1T [256][224] bf16;  W2 [256][64] -> W2T [64][256] bf16
__global__ void prep_weights(const float* __restrict__ W1,
                             const float* __restrict__ W2,
                             short* __restrict__ W1T,
                             short* __restrict__ W2T) {
  int idx = blockIdx.x * 256 + threadIdx.x;
  if (idx < 224 * 256) {
    int k = idx >> 8, n = idx & 255;
    W1T[n * 224 + k] = f2bf(W1[idx]);
  } else {
    int i2 = idx - 224 * 256;
    if (i2 < 256 * 64) {
      int k = i2 >> 6, n = i2 & 63;
      W2T[n * 256 + k] = f2bf(W2[i2]);
    }
  }
}

__global__ __launch_bounds__(1024, 4) void edge_mlp(
    const float* __restrict__ edges,
    const float* __restrict__ nodes,
    const float* __restrict__ glob,
    const int* __restrict__ recv,
    const int* __restrict__ send,
    const int* __restrict__ egi,
    const short* __restrict__ W1T,
    const short* __restrict__ W2T,
    const float* __restrict__ b1,
    const float* __restrict__ b2,
    float* __restrict__ out)
{
  __shared__ short X[128 * KPAD];   // 59,392 B
  __shared__ short H[128 * NPAD];   // 67,584 B   (total 126,976 <= 160 KiB)

  const int u    = threadIdx.x;
  const int lane = u & 63;
  const int w    = u >> 6;          // wave 0..15
  const int l    = lane & 15;
  const int g4   = lane >> 4;       // 0..3

  // staging roles: 8 threads per edge-row
  const int srow = u >> 3;          // 0..127
  const int sq   = u & 7;           // 0..7

  // layer-1 roles: wave owns n-cols [n0, n0+32), m-tiles mh..mh+3
  const int n0 = (w & 7) * 32;
  const int mh = (w >> 3) * 4;

  // layer-2 roles: wave owns m-tile mi2, out-col tiles j2a, j2a+1
  const int mi2 = w & 7;
  const int j2a = (w >> 3) * 2;

  // Preload W1 fragments for nt=0 (held in VGPRs for the whole block): 28 regs
  bf16x8 wf0[7];
  #pragma unroll
  for (int k = 0; k < 7; ++k)
    wf0[k] = *reinterpret_cast<const bf16x8*>(&W1T[(n0 + l) * 224 + k * 32 + g4 * 8]);
  const short* w1b = &W1T[(n0 + 16 + l) * 224 + g4 * 8];   // nt=1, loaded per k (L2-hot)

  int tile = blockIdx.x;

  // ---- prologue: issue register-staged loads for the first tile ----
  float4 re0, re1, rr0, rr1, rs0, rs1, rg0;
  {
    const int e0 = tile * 128;
    const float* ep = edges + (size_t)e0 * 64;
    re0 = *reinterpret_cast<const float4*>(ep + u * 4);
    re1 = *reinterpret_cast<const float4*>(ep + 4096 + u * 4);
    const int ir = recv[e0 + srow];
    const int is = send[e0 + srow];
    const int ig = egi[e0 + srow];
    const float* rp = nodes + (size_t)ir * 64;
    rr0 = *reinterpret_cast<const float4*>(rp + sq * 4);
    rr1 = *reinterpret_cast<const float4*>(rp + 32 + sq * 4);
    const float* sp = nodes + (size_t)is * 64;
    rs0 = *reinterpret_cast<const float4*>(sp + sq * 4);
    rs1 = *reinterpret_cast<const float4*>(sp + 32 + sq * 4);
    rg0 = *reinterpret_cast<const float4*>(glob + (size_t)ig * 32 + sq * 4);
  }

  for (; tile < NT_TILES; tile += NBLK) {
    const int e0  = tile * 128;
    const int nxt = tile + NBLK;

    // indices for next tile first (their latency hides under the X writes)
    int ir2 = 0, is2 = 0, ig2 = 0;
    if (nxt < NT_TILES) {
      const int e0n = nxt * 128;
      ir2 = recv[e0n + srow];
      is2 = send[e0n + srow];
      ig2 = egi[e0n + srow];
    }

    // ---- write X(t) from staged regs (compiler waits on the loads) ----
    *reinterpret_cast<short4*>(&X[(u >> 4) * KPAD + (u & 15) * 4])        = pk4(re0);
    *reinterpret_cast<short4*>(&X[(64 + (u >> 4)) * KPAD + (u & 15) * 4]) = pk4(re1);
    {
      short* xr = &X[srow * KPAD];
      *reinterpret_cast<short4*>(xr +  64 + sq * 4) = pk4(rr0);
      *reinterpret_cast<short4*>(xr +  96 + sq * 4) = pk4(rr1);
      *reinterpret_cast<short4*>(xr + 128 + sq * 4) = pk4(rs0);
      *reinterpret_cast<short4*>(xr + 160 + sq * 4) = pk4(rs1);
      *reinterpret_cast<short4*>(xr + 192 + sq * 4) = pk4(rg0);
    }

    // ---- issue loads for X(t+1); they stay in flight through L1+L2 ----
    if (nxt < NT_TILES) {
      const int e0n = nxt * 128;
      const float* ep = edges + (size_t)e0n * 64;
      re0 = *reinterpret_cast<const float4*>(ep + u * 4);
      re1 = *reinterpret_cast<const float4*>(ep + 4096 + u * 4);
      const float* rp = nodes + (size_t)ir2 * 64;
      rr0 = *reinterpret_cast<const float4*>(rp + sq * 4);
      rr1 = *reinterpret_cast<const float4*>(rp + 32 + sq * 4);
      const float* sp = nodes + (size_t)is2 * 64;
      rs0 = *reinterpret_cast<const float4*>(sp + sq * 4);
      rs1 = *reinterpret_cast<const float4*>(sp + 32 + sq * 4);
      rg0 = *reinterpret_cast<const float4*>(glob + (size_t)ig2 * 32 + sq * 4);
    }

    barrier_lds();   // B1: X(t) visible to all waves

    // ---- layer 1: swapped MFMA, D[n][m] = W1T-frag x X-frag ----
    f32x4 acc[4][2];
    #pragma unroll
    for (int mi = 0; mi < 4; ++mi) {
      acc[mi][0] = f32x4{0.f, 0.f, 0.f, 0.f};
      acc[mi][1] = f32x4{0.f, 0.f, 0.f, 0.f};
    }
    #pragma unroll
    for (int k = 0; k < 7; ++k) {
      bf16x8 wf1 = *reinterpret_cast<const bf16x8*>(w1b + k * 32);
      #pragma unroll
      for (int mi = 0; mi < 4; ++mi) {
        bf16x8 xa = *reinterpret_cast<const bf16x8*>(
            &X[((mh + mi) * 16 + l) * KPAD + k * 32 + g4 * 8]);
        acc[mi][0] = __builtin_amdgcn_mfma_f32_16x16x32_bf16(wf0[k], xa, acc[mi][0], 0, 0, 0);
        acc[mi][1] = __builtin_amdgcn_mfma_f32_16x16x32_bf16(wf1,    xa, acc[mi][1], 0, 0, 0);
      }
    }

    // ---- H epilogue: lane holds 4 consecutive n per (mi,nt) -> one b64 write ----
    #pragma unroll
    for (int nt = 0; nt < 2; ++nt) {
      const float4 bb = *reinterpret_cast<const float4*>(&b1[n0 + nt * 16 + g4 * 4]);
      #pragma unroll
      for (int mi = 0; mi < 4; ++mi) {
        float4 v;
        v.x = acc[mi][nt][0] + bb.x;
        v.y = acc[mi][nt][1] + bb.y;
        v.z = acc[mi][nt][2] + bb.z;
        v.w = acc[mi][nt][3] + bb.w;
        v.x = v.x > 0.f ? v.x : 0.f;
        v.y = v.y > 0.f ? v.y : 0.f;
        v.z = v.z > 0.f ? v.z : 0.f;
        v.w = v.w > 0.f ? v.w : 0.f;
        *reinterpret_cast<short4*>(
            &H[((mh + mi) * 16 + l) * NPAD + n0 + nt * 16 + g4 * 4]) = pk4(v);
      }
    }

    barrier_lds();   // B2: H(t) visible; also orders L1 X-reads before X(t+1) writes

    // ---- layer 2: D[ocol][m] = W2T-frag x H-frag ----
    f32x4 acc2[2];
    acc2[0] = f32x4{0.f, 0.f, 0.f, 0.f};
    acc2[1] = f32x4{0.f, 0.f, 0.f, 0.f};
    #pragma unroll
    for (int k = 0; k < 8; ++k) {
      bf16x8 hb = *reinterpret_cast<const bf16x8*>(
          &H[(mi2 * 16 + l) * NPAD + k * 32 + g4 * 8]);
      bf16x8 wa0 = *reinterpret_cast<const bf16x8*>(
          &W2T[((j2a + 0) * 16 + l) * 256 + k * 32 + g4 * 8]);
      bf16x8 wa1 = *reinterpret_cast<const bf16x8*>(
          &W2T[((j2a + 1) * 16 + l) * 256 + k * 32 + g4 * 8]);
      acc2[0] = __builtin_amdgcn_mfma_f32_16x16x32_bf16(wa0, hb, acc2[0], 0, 0, 0);
      acc2[1] = __builtin_amdgcn_mfma_f32_16x16x32_bf16(wa1, hb, acc2[1], 0, 0, 0);
    }

    // ---- out epilogue: lane holds 4 consecutive out cols -> dwordx4 stores ----
    #pragma unroll
    for (int jj = 0; jj < 2; ++jj) {
      const int oc = (j2a + jj) * 16 + g4 * 4;
      const float4 bb = *reinterpret_cast<const float4*>(&b2[oc]);
      float4 o;
      o.x = acc2[jj][0] + bb.x;
      o.y = acc2[jj][1] + bb.y;
      o.z = acc2[jj][2] + bb.z;
      o.w = acc2[jj][3] + bb.w;
      *reinterpret_cast<float4*>(&out[(size_t)(e0 + mi2 * 16 + l) * 64 + oc]) = o;
    }
    // loop back: X(t+1) writes are ordered after B2 (all L1 X-reads done)
  }
}

extern "C" void kernel_launch(void* const* d_in, const int* in_sizes, int n_in,
                              void* d_out, int out_size, void* d_ws, size_t ws_size,
                              hipStream_t stream) {
  (void)in_sizes; (void)n_in; (void)out_size; (void)ws_size;
  const float* edges = (const float*)d_in[0];
  const float* nodes = (const float*)d_in[1];
  const float* glob  = (const float*)d_in[2];
  const int*   recv  = (const int*)d_in[3];
  const int*   send  = (const int*)d_in[4];
  const int*   egi   = (const int*)d_in[5];
  const float* W1    = (const float*)d_in[6];
  const float* b1    = (const float*)d_in[7];
  const float* W2    = (const float*)d_in[8];
  const float* b2    = (const float*)d_in[9];
  float* out = (float*)d_out;

  short* W1T = (short*)d_ws;            // 256*224 bf16
  short* W2T = W1T + 256 * 224;         // 64*256 bf16

  prep_weights<<<288, 256, 0, stream>>>(W1, W2, W1T, W2T);
  edge_mlp<<<NBLK, 1024, 0, stream>>>(edges, nodes, glob, recv, send, egi,
                                      W1T, W2T, b1, b2, out);
}

// Round 3
// 265.436 us; speedup vs baseline: 1.8423x; 1.8423x over previous
//
#include <hip/hip_runtime.h>
#include <hip/hip_bf16.h>

typedef __attribute__((ext_vector_type(8))) short bf16x8;
typedef __attribute__((ext_vector_type(4))) float f32x4;

#define BM   128
#define KPAD 232   // X row stride in shorts (464B, 16B-aligned)
#define NPAD 264   // H row stride in shorts (528B, 16B-aligned)

static __device__ __forceinline__ short f2bf(float x) {
  union { __hip_bfloat16 h; short s; } u; u.h = __float2bfloat16(x); return u.s;
}
static __device__ __forceinline__ short4 pk4(float4 v) {
  short4 s; s.x = f2bf(v.x); s.y = f2bf(v.y); s.z = f2bf(v.z); s.w = f2bf(v.w);
  return s;
}

// W1 [224][256] -> W1T [256][224] bf16;  W2 [256][64] -> W2T [64][256] bf16
__global__ void prep_weights(const float* __restrict__ W1,
                             const float* __restrict__ W2,
                             short* __restrict__ W1T,
                             short* __restrict__ W2T) {
  int idx = blockIdx.x * 256 + threadIdx.x;
  if (idx < 224 * 256) {
    int k = idx >> 8, n = idx & 255;
    W1T[n * 224 + k] = f2bf(W1[idx]);
  } else {
    int i2 = idx - 224 * 256;
    if (i2 < 256 * 64) {
      int k = i2 >> 6, n = i2 & 63;
      W2T[n * 256 + k] = f2bf(W2[i2]);
    }
  }
}

__global__ __launch_bounds__(512, 4) void edge_mlp(
    const float* __restrict__ edges,
    const float* __restrict__ nodes,
    const float* __restrict__ glob,
    const int* __restrict__ recv,
    const int* __restrict__ send,
    const int* __restrict__ egi,
    const short* __restrict__ W1T,
    const short* __restrict__ W2T,
    const float* __restrict__ b1,
    const float* __restrict__ b2,
    float* __restrict__ out)
{
  // One buffer, two lives: X tile [128][KPAD], then H tile [128][NPAD].
  __shared__ short S[BM * NPAD];   // 67,584 B -> 2 blocks/CU

  const int t    = threadIdx.x;
  const int e0   = blockIdx.x * BM;
  const int lane = t & 63;
  const int w    = t >> 6;        // wave 0..7
  const int l    = lane & 15;
  const int g4   = lane >> 4;     // 0..3

  // ---- stage X = [edges | nodes[recv] | nodes[send] | glob] as bf16 ----
  // 8 threads per gathered row: each wave-load touches 8 rows x 128B contiguous.
  {
    const int r8 = t >> 3;        // 0..63
    const int sq = t & 7;         // 0..7

    const int ir0 = recv[e0 + r8];
    const int ir1 = recv[e0 + 64 + r8];
    const int is0 = send[e0 + r8];
    const int is1 = send[e0 + 64 + r8];
    const int ig0 = egi[e0 + r8];
    const int ig1 = egi[e0 + 64 + r8];

    const float* ebase = edges + (size_t)e0 * 64;
    float4 ev0 = *reinterpret_cast<const float4*>(ebase + t * 4);
    float4 ev1 = *reinterpret_cast<const float4*>(ebase + 2048 + t * 4);
    float4 ev2 = *reinterpret_cast<const float4*>(ebase + 4096 + t * 4);
    float4 ev3 = *reinterpret_cast<const float4*>(ebase + 6144 + t * 4);

    const float* rp0 = nodes + (size_t)ir0 * 64;
    const float* rp1 = nodes + (size_t)ir1 * 64;
    const float* sp0 = nodes + (size_t)is0 * 64;
    const float* sp1 = nodes + (size_t)is1 * 64;
    float4 r0a = *reinterpret_cast<const float4*>(rp0 + sq * 4);
    float4 r0b = *reinterpret_cast<const float4*>(rp0 + 32 + sq * 4);
    float4 r1a = *reinterpret_cast<const float4*>(rp1 + sq * 4);
    float4 r1b = *reinterpret_cast<const float4*>(rp1 + 32 + sq * 4);
    float4 s0a = *reinterpret_cast<const float4*>(sp0 + sq * 4);
    float4 s0b = *reinterpret_cast<const float4*>(sp0 + 32 + sq * 4);
    float4 s1a = *reinterpret_cast<const float4*>(sp1 + sq * 4);
    float4 s1b = *reinterpret_cast<const float4*>(sp1 + 32 + sq * 4);
    float4 g0  = *reinterpret_cast<const float4*>(glob + (size_t)ig0 * 32 + sq * 4);
    float4 g1  = *reinterpret_cast<const float4*>(glob + (size_t)ig1 * 32 + sq * 4);

    // edges: f4idx = it*512 + t -> row = it*32 + (t>>4), col = (t&15)*4
    const int erow = t >> 4, ecol = (t & 15) * 4;
    *reinterpret_cast<short4*>(&S[(erow      ) * KPAD + ecol]) = pk4(ev0);
    *reinterpret_cast<short4*>(&S[(erow + 32 ) * KPAD + ecol]) = pk4(ev1);
    *reinterpret_cast<short4*>(&S[(erow + 64 ) * KPAD + ecol]) = pk4(ev2);
    *reinterpret_cast<short4*>(&S[(erow + 96 ) * KPAD + ecol]) = pk4(ev3);

    short* xr0 = &S[r8 * KPAD];
    short* xr1 = &S[(64 + r8) * KPAD];
    *reinterpret_cast<short4*>(xr0 +  64 + sq * 4) = pk4(r0a);
    *reinterpret_cast<short4*>(xr0 +  96 + sq * 4) = pk4(r0b);
    *reinterpret_cast<short4*>(xr1 +  64 + sq * 4) = pk4(r1a);
    *reinterpret_cast<short4*>(xr1 +  96 + sq * 4) = pk4(r1b);
    *reinterpret_cast<short4*>(xr0 + 128 + sq * 4) = pk4(s0a);
    *reinterpret_cast<short4*>(xr0 + 160 + sq * 4) = pk4(s0b);
    *reinterpret_cast<short4*>(xr1 + 128 + sq * 4) = pk4(s1a);
    *reinterpret_cast<short4*>(xr1 + 160 + sq * 4) = pk4(s1b);
    *reinterpret_cast<short4*>(xr0 + 192 + sq * 4) = pk4(g0);
    *reinterpret_cast<short4*>(xr1 + 192 + sq * 4) = pk4(g1);
  }
  __syncthreads();

  // ---- layer 1 (swapped): D[n][m] = W1T-frag x X-frag ----
  // wave owns n-cols [n0, n0+64) (4 n-tiles) and m-tiles mh..mh+3 (64 rows)
  const int n0 = (w & 3) * 64;
  const int mh = (w >> 2) * 4;

  const short* wbase = W1T + (size_t)(n0 + l) * 224 + g4 * 8;

  f32x4 acc[4][4];
  #pragma unroll
  for (int mi = 0; mi < 4; ++mi)
    #pragma unroll
    for (int nt = 0; nt < 4; ++nt)
      acc[mi][nt] = f32x4{0.f, 0.f, 0.f, 0.f};

  bf16x8 wc[4], wn[4];
  #pragma unroll
  for (int nt = 0; nt < 4; ++nt)
    wn[nt] = *reinterpret_cast<const bf16x8*>(wbase + nt * 3584);   // 16*224

  #pragma unroll 1
  for (int k0 = 0; k0 < 224; k0 += 32) {
    #pragma unroll
    for (int nt = 0; nt < 4; ++nt) wc[nt] = wn[nt];
    if (k0 + 32 < 224) {
      #pragma unroll
      for (int nt = 0; nt < 4; ++nt)
        wn[nt] = *reinterpret_cast<const bf16x8*>(wbase + nt * 3584 + k0 + 32);
    }
    #pragma unroll
    for (int mi = 0; mi < 4; ++mi) {
      bf16x8 xa = *reinterpret_cast<const bf16x8*>(
          &S[((mh + mi) * 16 + l) * KPAD + k0 + g4 * 8]);
      acc[mi][0] = __builtin_amdgcn_mfma_f32_16x16x32_bf16(wc[0], xa, acc[mi][0], 0, 0, 0);
      acc[mi][1] = __builtin_amdgcn_mfma_f32_16x16x32_bf16(wc[1], xa, acc[mi][1], 0, 0, 0);
      acc[mi][2] = __builtin_amdgcn_mfma_f32_16x16x32_bf16(wc[2], xa, acc[mi][2], 0, 0, 0);
      acc[mi][3] = __builtin_amdgcn_mfma_f32_16x16x32_bf16(wc[3], xa, acc[mi][3], 0, 0, 0);
    }
  }

  __syncthreads();   // all waves done reading X before S is reused as H

  // ---- H epilogue: lane holds 4 consecutive n per (mi,nt) -> short4 write ----
  #pragma unroll
  for (int nt = 0; nt < 4; ++nt) {
    const float4 bb = *reinterpret_cast<const float4*>(&b1[n0 + nt * 16 + g4 * 4]);
    #pragma unroll
    for (int mi = 0; mi < 4; ++mi) {
      float4 v;
      v.x = acc[mi][nt][0] + bb.x;
      v.y = acc[mi][nt][1] + bb.y;
      v.z = acc[mi][nt][2] + bb.z;
      v.w = acc[mi][nt][3] + bb.w;
      v.x = v.x > 0.f ? v.x : 0.f;
      v.y = v.y > 0.f ? v.y : 0.f;
      v.z = v.z > 0.f ? v.z : 0.f;
      v.w = v.w > 0.f ? v.w : 0.f;
      *reinterpret_cast<short4*>(
          &S[((mh + mi) * 16 + l) * NPAD + n0 + nt * 16 + g4 * 4]) = pk4(v);
    }
  }
  __syncthreads();

  // ---- layer 2 (swapped): D[oc][m]; wave owns oc-tile j2, m-tiles mh..mh+3 ----
  const int j2 = w & 3;
  const short* w2base = W2T + (size_t)(j2 * 16 + l) * 256 + g4 * 8;

  f32x4 acc2[4];
  #pragma unroll
  for (int mi = 0; mi < 4; ++mi) acc2[mi] = f32x4{0.f, 0.f, 0.f, 0.f};

  #pragma unroll
  for (int k0 = 0; k0 < 256; k0 += 32) {
    bf16x8 wf = *reinterpret_cast<const bf16x8*>(w2base + k0);
    #pragma unroll
    for (int mi = 0; mi < 4; ++mi) {
      bf16x8 hb = *reinterpret_cast<const bf16x8*>(
          &S[((mh + mi) * 16 + l) * NPAD + k0 + g4 * 8]);
      acc2[mi] = __builtin_amdgcn_mfma_f32_16x16x32_bf16(wf, hb, acc2[mi], 0, 0, 0);
    }
  }

  // ---- out: lane holds 4 consecutive out cols -> float4 stores ----
  {
    const float4 bb = *reinterpret_cast<const float4*>(&b2[j2 * 16 + g4 * 4]);
    #pragma unroll
    for (int mi = 0; mi < 4; ++mi) {
      float4 o;
      o.x = acc2[mi][0] + bb.x;
      o.y = acc2[mi][1] + bb.y;
      o.z = acc2[mi][2] + bb.z;
      o.w = acc2[mi][3] + bb.w;
      *reinterpret_cast<float4*>(
          &out[(size_t)(e0 + (mh + mi) * 16 + l) * 64 + j2 * 16 + g4 * 4]) = o;
    }
  }
}

extern "C" void kernel_launch(void* const* d_in, const int* in_sizes, int n_in,
                              void* d_out, int out_size, void* d_ws, size_t ws_size,
                              hipStream_t stream) {
  (void)in_sizes; (void)n_in; (void)out_size; (void)ws_size;
  const float* edges = (const float*)d_in[0];
  const float* nodes = (const float*)d_in[1];
  const float* glob  = (const float*)d_in[2];
  const int*   recv  = (const int*)d_in[3];
  const int*   send  = (const int*)d_in[4];
  const int*   egi   = (const int*)d_in[5];
  const float* W1    = (const float*)d_in[6];
  const float* b1    = (const float*)d_in[7];
  const float* W2    = (const float*)d_in[8];
  const float* b2    = (const float*)d_in[9];
  float* out = (float*)d_out;

  short* W1T = (short*)d_ws;            // 256*224 bf16
  short* W2T = W1T + 256 * 224;         // 64*256 bf16

  prep_weights<<<288, 256, 0, stream>>>(W1, W2, W1T, W2T);
  edge_mlp<<<800000 / BM, 512, 0, stream>>>(edges, nodes, glob, recv, send, egi,
                                            W1T, W2T, b1, b2, out);
}

// Round 4
// 233.526 us; speedup vs baseline: 2.0941x; 1.1366x over previous
//
#include <hip/hip_runtime.h>
#include <hip/hip_bf16.h>

typedef __attribute__((ext_vector_type(8))) short bf16x8;
typedef __attribute__((ext_vector_type(4))) float f32x4;

#define BM 64
// S tile: [64 rows][256 shorts] = 32 KiB exactly -> 5 blocks/CU.
// Row stride 512B is bank-degenerate, so every access goes through a
// 16B-chunk XOR swizzle: col ^ ((row&7)<<3)  (chunk = 8 shorts = 16B).
#define SIDX(r, c) (((r) << 8) + ((c) ^ (((r) & 7) << 3)))

static __device__ __forceinline__ short f2bf(float x) {
  union { __hip_bfloat16 h; short s; } u; u.h = __float2bfloat16(x); return u.s;
}
static __device__ __forceinline__ short4 pk4(float4 v) {
  short4 s; s.x = f2bf(v.x); s.y = f2bf(v.y); s.z = f2bf(v.z); s.w = f2bf(v.w);
  return s;
}

// W1 [224][256] -> W1T [256][224] bf16;  W2 [256][64] -> W2T [64][256] bf16
__global__ void prep_weights(const float* __restrict__ W1,
                             const float* __restrict__ W2,
                             short* __restrict__ W1T,
                             short* __restrict__ W2T) {
  int idx = blockIdx.x * 256 + threadIdx.x;
  if (idx < 224 * 256) {
    int k = idx >> 8, n = idx & 255;
    W1T[n * 224 + k] = f2bf(W1[idx]);
  } else {
    int i2 = idx - 224 * 256;
    if (i2 < 256 * 64) {
      int k = i2 >> 6, n = i2 & 63;
      W2T[n * 256 + k] = f2bf(W2[i2]);
    }
  }
}

__global__ __launch_bounds__(256, 5) void edge_mlp(
    const float* __restrict__ edges,
    const float* __restrict__ nodes,
    const float* __restrict__ glob,
    const int* __restrict__ recv,
    const int* __restrict__ send,
    const int* __restrict__ egi,
    const short* __restrict__ W1T,
    const short* __restrict__ W2T,
    const float* __restrict__ b1,
    const float* __restrict__ b2,
    float* __restrict__ out)
{
  __shared__ short S[BM * 256];   // 32,768 B

  const int t    = threadIdx.x;
  const int e0   = blockIdx.x * BM;
  const int lane = t & 63;
  const int w    = t >> 6;        // wave 0..3
  const int l    = lane & 15;
  const int g4   = lane >> 4;     // 0..3

  // ---- stage X = [edges | nodes[recv] | nodes[send] | glob] as bf16 ----
  // 8 threads per gathered row; each thread covers 2 rows (r8, r8+32).
  {
    const int r8 = t >> 3;        // 0..31
    const int sq = t & 7;         // 0..7

    const int ir0 = recv[e0 + r8];
    const int ir1 = recv[e0 + 32 + r8];
    const int is0 = send[e0 + r8];
    const int is1 = send[e0 + 32 + r8];
    const int ig0 = egi[e0 + r8];
    const int ig1 = egi[e0 + 32 + r8];

    const float* ebase = edges + (size_t)e0 * 64;
    float4 ev0 = *reinterpret_cast<const float4*>(ebase + t * 4);
    float4 ev1 = *reinterpret_cast<const float4*>(ebase + 1024 + t * 4);
    float4 ev2 = *reinterpret_cast<const float4*>(ebase + 2048 + t * 4);
    float4 ev3 = *reinterpret_cast<const float4*>(ebase + 3072 + t * 4);

    const float* rp0 = nodes + (size_t)ir0 * 64;
    const float* rp1 = nodes + (size_t)ir1 * 64;
    const float* sp0 = nodes + (size_t)is0 * 64;
    const float* sp1 = nodes + (size_t)is1 * 64;
    float4 r0a = *reinterpret_cast<const float4*>(rp0 + sq * 4);
    float4 r0b = *reinterpret_cast<const float4*>(rp0 + 32 + sq * 4);
    float4 r1a = *reinterpret_cast<const float4*>(rp1 + sq * 4);
    float4 r1b = *reinterpret_cast<const float4*>(rp1 + 32 + sq * 4);
    float4 s0a = *reinterpret_cast<const float4*>(sp0 + sq * 4);
    float4 s0b = *reinterpret_cast<const float4*>(sp0 + 32 + sq * 4);
    float4 s1a = *reinterpret_cast<const float4*>(sp1 + sq * 4);
    float4 s1b = *reinterpret_cast<const float4*>(sp1 + 32 + sq * 4);
    float4 g0  = *reinterpret_cast<const float4*>(glob + (size_t)ig0 * 32 + sq * 4);
    float4 g1  = *reinterpret_cast<const float4*>(glob + (size_t)ig1 * 32 + sq * 4);

    // edges: f4 index f = it*256 + t -> row = f>>4, feature col = (f&15)*4
    const int erow = t >> 4, ecol = (t & 15) * 4;
    *reinterpret_cast<short4*>(&S[SIDX(erow,      ecol)]) = pk4(ev0);
    *reinterpret_cast<short4*>(&S[SIDX(erow + 16, ecol)]) = pk4(ev1);
    *reinterpret_cast<short4*>(&S[SIDX(erow + 32, ecol)]) = pk4(ev2);
    *reinterpret_cast<short4*>(&S[SIDX(erow + 48, ecol)]) = pk4(ev3);

    *reinterpret_cast<short4*>(&S[SIDX(r8,       64 + sq * 4)]) = pk4(r0a);
    *reinterpret_cast<short4*>(&S[SIDX(r8,       96 + sq * 4)]) = pk4(r0b);
    *reinterpret_cast<short4*>(&S[SIDX(32 + r8,  64 + sq * 4)]) = pk4(r1a);
    *reinterpret_cast<short4*>(&S[SIDX(32 + r8,  96 + sq * 4)]) = pk4(r1b);
    *reinterpret_cast<short4*>(&S[SIDX(r8,      128 + sq * 4)]) = pk4(s0a);
    *reinterpret_cast<short4*>(&S[SIDX(r8,      160 + sq * 4)]) = pk4(s0b);
    *reinterpret_cast<short4*>(&S[SIDX(32 + r8, 128 + sq * 4)]) = pk4(s1a);
    *reinterpret_cast<short4*>(&S[SIDX(32 + r8, 160 + sq * 4)]) = pk4(s1b);
    *reinterpret_cast<short4*>(&S[SIDX(r8,      192 + sq * 4)]) = pk4(g0);
    *reinterpret_cast<short4*>(&S[SIDX(32 + r8, 192 + sq * 4)]) = pk4(g1);
  }
  __syncthreads();

  // ---- layer 1 (swapped): D[n][m] = W1T-frag x X-frag ----
  // wave owns n-cols [w*64, w*64+64) (4 n-tiles) x all 4 m-tiles (64 rows)
  const int n0 = w * 64;
  const short* wbase = W1T + (size_t)(n0 + l) * 224 + g4 * 8;

  f32x4 acc[4][4];
  #pragma unroll
  for (int mi = 0; mi < 4; ++mi)
    #pragma unroll
    for (int nt = 0; nt < 4; ++nt)
      acc[mi][nt] = f32x4{0.f, 0.f, 0.f, 0.f};

  __builtin_amdgcn_s_setprio(1);
  #pragma unroll 1
  for (int k0 = 0; k0 < 224; k0 += 32) {
    bf16x8 wc0 = *reinterpret_cast<const bf16x8*>(wbase + k0);
    bf16x8 wc1 = *reinterpret_cast<const bf16x8*>(wbase + 3584 + k0);   // 16*224
    bf16x8 wc2 = *reinterpret_cast<const bf16x8*>(wbase + 7168 + k0);
    bf16x8 wc3 = *reinterpret_cast<const bf16x8*>(wbase + 10752 + k0);
    #pragma unroll
    for (int mi = 0; mi < 4; ++mi) {
      bf16x8 xa = *reinterpret_cast<const bf16x8*>(&S[SIDX(mi * 16 + l, k0 + g4 * 8)]);
      acc[mi][0] = __builtin_amdgcn_mfma_f32_16x16x32_bf16(wc0, xa, acc[mi][0], 0, 0, 0);
      acc[mi][1] = __builtin_amdgcn_mfma_f32_16x16x32_bf16(wc1, xa, acc[mi][1], 0, 0, 0);
      acc[mi][2] = __builtin_amdgcn_mfma_f32_16x16x32_bf16(wc2, xa, acc[mi][2], 0, 0, 0);
      acc[mi][3] = __builtin_amdgcn_mfma_f32_16x16x32_bf16(wc3, xa, acc[mi][3], 0, 0, 0);
    }
  }
  __builtin_amdgcn_s_setprio(0);

  __syncthreads();   // all waves done reading X before S is reused as H

  // ---- H epilogue: lane holds 4 consecutive n per (mi,nt) -> short4 write ----
  #pragma unroll
  for (int nt = 0; nt < 4; ++nt) {
    const float4 bb = *reinterpret_cast<const float4*>(&b1[n0 + nt * 16 + g4 * 4]);
    #pragma unroll
    for (int mi = 0; mi < 4; ++mi) {
      float4 v;
      v.x = acc[mi][nt][0] + bb.x;
      v.y = acc[mi][nt][1] + bb.y;
      v.z = acc[mi][nt][2] + bb.z;
      v.w = acc[mi][nt][3] + bb.w;
      v.x = v.x > 0.f ? v.x : 0.f;
      v.y = v.y > 0.f ? v.y : 0.f;
      v.z = v.z > 0.f ? v.z : 0.f;
      v.w = v.w > 0.f ? v.w : 0.f;
      *reinterpret_cast<short4*>(
          &S[SIDX(mi * 16 + l, n0 + nt * 16 + g4 * 4)]) = pk4(v);
    }
  }
  __syncthreads();

  // ---- layer 2 (swapped): D[oc][m]; wave owns oc-tile w, all 4 m-tiles ----
  const short* w2base = W2T + (size_t)(w * 16 + l) * 256 + g4 * 8;

  f32x4 acc2[4];
  #pragma unroll
  for (int mi = 0; mi < 4; ++mi) acc2[mi] = f32x4{0.f, 0.f, 0.f, 0.f};

  __builtin_amdgcn_s_setprio(1);
  #pragma unroll 1
  for (int k0 = 0; k0 < 256; k0 += 32) {
    bf16x8 wf = *reinterpret_cast<const bf16x8*>(w2base + k0);
    #pragma unroll
    for (int mi = 0; mi < 4; ++mi) {
      bf16x8 hb = *reinterpret_cast<const bf16x8*>(&S[SIDX(mi * 16 + l, k0 + g4 * 8)]);
      acc2[mi] = __builtin_amdgcn_mfma_f32_16x16x32_bf16(wf, hb, acc2[mi], 0, 0, 0);
    }
  }
  __builtin_amdgcn_s_setprio(0);

  // ---- out: lane holds 4 consecutive out cols -> float4 stores ----
  {
    const float4 bb = *reinterpret_cast<const float4*>(&b2[w * 16 + g4 * 4]);
    #pragma unroll
    for (int mi = 0; mi < 4; ++mi) {
      float4 o;
      o.x = acc2[mi][0] + bb.x;
      o.y = acc2[mi][1] + bb.y;
      o.z = acc2[mi][2] + bb.z;
      o.w = acc2[mi][3] + bb.w;
      *reinterpret_cast<float4*>(
          &out[(size_t)(e0 + mi * 16 + l) * 64 + w * 16 + g4 * 4]) = o;
    }
  }
}

extern "C" void kernel_launch(void* const* d_in, const int* in_sizes, int n_in,
                              void* d_out, int out_size, void* d_ws, size_t ws_size,
                              hipStream_t stream) {
  (void)in_sizes; (void)n_in; (void)out_size; (void)ws_size;
  const float* edges = (const float*)d_in[0];
  const float* nodes = (const float*)d_in[1];
  const float* glob  = (const float*)d_in[2];
  const int*   recv  = (const int*)d_in[3];
  const int*   send  = (const int*)d_in[4];
  const int*   egi   = (const int*)d_in[5];
  const float* W1    = (const float*)d_in[6];
  const float* b1    = (const float*)d_in[7];
  const float* W2    = (const float*)d_in[8];
  const float* b2    = (const float*)d_in[9];
  float* out = (float*)d_out;

  short* W1T = (short*)d_ws;            // 256*224 bf16
  short* W2T = W1T + 256 * 224;         // 64*256 bf16

  prep_weights<<<288, 256, 0, stream>>>(W1, W2, W1T, W2T);
  edge_mlp<<<800000 / BM, 256, 0, stream>>>(edges, nodes, glob, recv, send, egi,
                                            W1T, W2T, b1, b2, out);
}